// Round 16
// baseline (120.665 us; speedup 1.0000x reference)
//
#include <hip/hip_runtime.h>
#include <hip/hip_fp16.h>

#define HH 384
#define WW 384
#define HW (HH * WW)            // 147456
#define NIMG 128                // B*G
#define NPIX (NIMG * HW)        // 18874368
#define GRAD_CNT 37650432.0

// K1: full-width tiles, 8 rows, +/-3 staged margin, 14 pair-rows LDS (21 KB)
// x-pair layout: element (r,x) = half2(img[r][x], img[r][min(x+1,383)])
#define K1_TH 8
#define K1_M  3
#define K1_NT (HH / K1_TH)              // 48
#define K1_SROWS (K1_TH + 2 * K1_M)     // 14
#define NP_G (K1_NT * NIMG)             // 6144

// K2: n-split into 8 partial template planes, combined once by K2b
#define K2_SPLIT 8

// K3 tiling: 32x32 tiles, 2 n-planes per block, staged window 40 cols
#define K3_T 32
#define K3_NX (WW / K3_T)               // 12
#define K3_TILES (K3_NX * (HH / K3_T)) // 144
#define NP_N (K3_TILES * NIMG)          // 18432

// ---- block reductions (256 threads = 4 waves) ------------------------------
__device__ inline void block_reduce_store_256(float v, float* dst) {
    #pragma unroll
    for (int o = 32; o > 0; o >>= 1) v += __shfl_down(v, o);
    __shared__ float s[4];
    int wave = threadIdx.x >> 6, lane = threadIdx.x & 63;
    if (lane == 0) s[wave] = v;
    __syncthreads();
    if (threadIdx.x == 0) *dst = s[0] + s[1] + s[2] + s[3];
}

__device__ inline void block_reduce_store2_256(float v0, float v1,
                                               float* d0, float* d1) {
    #pragma unroll
    for (int o = 32; o > 0; o >>= 1) {
        v0 += __shfl_down(v0, o);
        v1 += __shfl_down(v1, o);
    }
    __shared__ float s0[4], s1[4];
    int wave = threadIdx.x >> 6, lane = threadIdx.x & 63;
    if (lane == 0) { s0[wave] = v0; s1[wave] = v1; }
    __syncthreads();
    if (threadIdx.x == 0) {
        *d0 = s0[0] + s0[1] + s0[2] + s0[3];
        *d1 = s1[0] + s1[1] + s1[2] + s1[3];
    }
}

// ---- K1: bilinear warp; f-row flow loads prefetched for MLP ----------------
__global__ __launch_bounds__(256, 6) void warp_grad_kernel(
        const float* __restrict__ images, const float* __restrict__ warps,
        __half* __restrict__ warped, float* __restrict__ partialsG) {
    __shared__ __half2 simg[K1_SROWS * WW];      // 21 KB
    int n = blockIdx.y;
    int yt = blockIdx.x;
    int y0 = yt * K1_TH;
    int ys0 = max(0, y0 - K1_M);
    int ys1 = min(HH - 1, y0 + K1_TH - 1 + K1_M);
    int cnt = ys1 - ys0 + 1;                  // <= 14
    const float* img = images + (size_t)n * HW;
    int tid = threadIdx.x;

    const float* flow0 = warps + (size_t)n * 2 * HW;
    const float* flow1 = flow0 + HW;

    // stage pair-rows [ys0, ys1]: float4 read + shfl neighbor -> 4 half2 pairs
    for (int i = tid; i < cnt * 96; i += 256) {
        int r = i / 96, gg = i - r * 96;
        int x0 = gg * 4;
        const float* rowp = img + (ys0 + r) * WW + x0;
        float4 v = *(const float4*)rowp;
        float nb = __shfl_down(v.x, 1);       // next group's first element
        if (gg == 95) nb = v.w;               // row edge: duplicate
        else if ((tid & 63) == 63) nb = rowp[4];  // wave edge: scalar load
        union { __half2 h[4]; uint4 u; } pk;
        pk.h[0] = __floats2half2_rn(v.x, v.y);
        pk.h[1] = __floats2half2_rn(v.y, v.z);
        pk.h[2] = __floats2half2_rn(v.z, v.w);
        pk.h[3] = __floats2half2_rn(v.w, nb);
        *(uint4*)(simg + r * WW + x0) = pk.u; // 16B-aligned ds_write_b128
    }

    // ---- prefetch all 3 iterations' f-row flow loads (independent; in
    // flight across the barrier). b-rows deliberately NOT prefetched (L1).
    float4 fA0, fA1, fB0, fB1, fC0, fC1;
    {
        int pA = tid,        rA = pA / 96;
        int pB = 256 + tid,  rB = pB / 96;
        int pC = 512 + tid,  rC = pC / 96;
        int bA = (y0 + rA) * WW + (pA - rA * 96) * 4;
        int bB = (y0 + rB) * WW + (pB - rB * 96) * 4;
        int bC = (y0 + rC) * WW + (pC - rC * 96) * 4;
        fA0 = *(const float4*)(flow0 + bA); fA1 = *(const float4*)(flow1 + bA);
        fB0 = *(const float4*)(flow0 + bB); fB1 = *(const float4*)(flow1 + bB);
        fC0 = *(const float4*)(flow0 + bC); fC1 = *(const float4*)(flow1 + bC);
    }
    __syncthreads();

    float g = 0.f;

    #pragma unroll
    for (int gi = 0; gi < 3; ++gi) {          // 8 rows * 96 groups = 3 * 256
        int p4 = gi * 256 + tid;
        int r = p4 / 96;                      // tile row 0..7
        int c4 = p4 - r * 96;
        int x0 = c4 * 4;
        int y = y0 + r;
        int base = y * WW + x0;

        float4 f0 = (gi == 0) ? fA0 : (gi == 1) ? fB0 : fC0;
        float4 f1 = (gi == 0) ? fA1 : (gi == 1) ? fB1 : fC1;

        // right-neighbor first element via cross-lane (saves 2 scalar VMEM)
        float a0 = __shfl_down(f0.x, 1);
        float a1 = __shfl_down(f1.x, 1);
        if (c4 == 95) {                       // row edge: self-zero diff
            a0 = f0.w; a1 = f1.w;
        } else if ((tid & 63) == 63) {        // wave edge: 1-lane load
            a0 = flow0[base + 4]; a1 = flow1[base + 4];
        }

        // grad2d l2: dx within group + right neighbor, dy vs next row
        float d;
        d = f0.y - f0.x; g += d * d;  d = f1.y - f1.x; g += d * d;
        d = f0.z - f0.y; g += d * d;  d = f1.z - f1.y; g += d * d;
        d = f0.w - f0.z; g += d * d;  d = f1.w - f1.z; g += d * d;
        d = a0 - f0.w;   g += d * d;  d = a1 - f1.w;   g += d * d;
        if (y + 1 < HH) {
            float4 b0 = *(const float4*)(flow0 + base + WW);
            float4 b1 = *(const float4*)(flow1 + base + WW);
            d = b0.x - f0.x; g += d * d;  d = b1.x - f1.x; g += d * d;
            d = b0.y - f0.y; g += d * d;  d = b1.y - f1.y; g += d * d;
            d = b0.z - f0.z; g += d * d;  d = b1.z - f1.z; g += d * d;
            d = b0.w - f0.w; g += d * d;  d = b1.w - f1.w; g += d * d;
        }

        float fxa[4] = {f0.x, f0.y, f0.z, f0.w};
        float fya[4] = {f1.x, f1.y, f1.z, f1.w};

        // clamped coordinates (exact: out-of-range tap weights collapse)
        float cxc[4], cyc[4];
        #pragma unroll
        for (int j = 0; j < 4; ++j) {
            cxc[j] = fminf(fmaxf((float)(x0 + j) + fxa[j], 0.f), 383.f);
            cyc[j] = fminf(fmaxf((float)y + fya[j], 0.f), 383.f);
        }
        bool ok = true;
        #pragma unroll
        for (int j = 0; j < 4; ++j) {
            int yi = (int)cyc[j];
            ok = ok && (yi >= ys0) && (yi < ys1);
        }

        float o[4];
        if (ok) {
            // fast path: 2 ds_read_b32 per pixel, single address
            #pragma unroll
            for (int j = 0; j < 4; ++j) {
                int xi = (int)cxc[j], yi = (int)cyc[j];
                float wx = cxc[j] - (float)xi, wy = cyc[j] - (float)yi;
                const __half2* rp = simg + (yi - ys0) * WW + xi;
                float2 tp = __half22float2(rp[0]);
                float2 bt = __half22float2(rp[WW]);
                float top = fmaf(wx, tp.y - tp.x, tp.x);
                float bot = fmaf(wx, bt.y - bt.x, bt.x);
                o[j] = fmaf(wy, bot - top, top);
            }
        } else {
            // slow path (~1-2% of groups): exact f32 global taps
            #pragma unroll
            for (int j = 0; j < 4; ++j) {
                int xi = (int)cxc[j], yi = (int)cyc[j];
                float wx = cxc[j] - (float)xi, wy = cyc[j] - (float)yi;
                int x1 = min(xi + 1, WW - 1), y1 = min(yi + 1, HH - 1);
                float v00 = img[yi * WW + xi], v01 = img[yi * WW + x1];
                float v10 = img[y1 * WW + xi], v11 = img[y1 * WW + x1];
                float top = fmaf(wx, v01 - v00, v00);
                float bot = fmaf(wx, v11 - v10, v10);
                o[j] = fmaf(wy, bot - top, top);
            }
        }
        union { __half2 h2[2]; uint2 u; } cv;
        cv.h2[0] = __floats2half2_rn(o[0], o[1]);
        cv.h2[1] = __floats2half2_rn(o[2], o[3]);
        *(uint2*)(warped + (size_t)n * HW + base) = cv.u;
    }
    block_reduce_store_256(g, &partialsG[(size_t)n * K1_NT + yt]);
}

// ---- K2a: partial template sums (n split 8-ways, 8 px/thread, fp16 in) -----
__global__ __launch_bounds__(256) void template_part_kernel(
        const __half* __restrict__ warped, float* __restrict__ tpart) {
    int p8 = blockIdx.x * 256 + threadIdx.x;      // < HW/8 (grid.x = 72)
    int q = blockIdx.y;                           // 0..7
    const __half* p = warped + (size_t)q * (NIMG / K2_SPLIT) * HW + p8 * 8;
    float s[8] = {0, 0, 0, 0, 0, 0, 0, 0};
    #pragma unroll 4
    for (int nn = 0; nn < NIMG / K2_SPLIT; ++nn) {
        union { uint4 u; __half2 h2[4]; } cv;
        cv.u = *(const uint4*)(p + (size_t)nn * HW);
        #pragma unroll
        for (int k = 0; k < 4; ++k) {
            float2 f = __half22float2(cv.h2[k]);
            s[2 * k] += f.x; s[2 * k + 1] += f.y;
        }
    }
    float* dst = tpart + (size_t)q * HW + p8 * 8;
    *(float4*)dst       = make_float4(s[0], s[1], s[2], s[3]);
    *(float4*)(dst + 4) = make_float4(s[4], s[5], s[6], s[7]);
}

// ---- K2b: combine 8 planes -> templ (f32) ----------------------------------
__global__ __launch_bounds__(256) void template_combine_kernel(
        const float* __restrict__ tpart, float* __restrict__ templ) {
    int p4 = blockIdx.x * 256 + threadIdx.x;      // < HW/4 (144 blocks)
    float sx = 0, sy = 0, sz = 0, sw = 0;
    #pragma unroll
    for (int pl = 0; pl < K2_SPLIT; ++pl) {
        float4 a = *(const float4*)(tpart + (size_t)pl * HW + p4 * 4);
        sx += a.x; sy += a.y; sz += a.z; sw += a.w;
    }
    const float sc = 1.f / (float)NIMG;
    *(float4*)(templ + p4 * 4) = make_float4(sx * sc, sy * sc, sz * sc, sw * sc);
}

// ---- K3: LNCC, 2 n-planes per block, shared template stage -----------------
__global__ __launch_bounds__(256) void lncc_kernel(
        const __half* __restrict__ warped, const float* __restrict__ templ,
        float* __restrict__ partialsN) {
    __shared__ float st0[34][40];
    __shared__ float st1[34][40];
    __shared__ float sp[34][40];
    int n0 = blockIdx.y;                   // 0..63
    int n1 = n0 + 64;
    int tile = blockIdx.x;
    int tyt = tile / K3_NX, txt = tile - tyt * K3_NX;
    int oy0 = tyt * K3_T, ox0 = txt * K3_T;
    const __half* t0 = warped + (size_t)n0 * HW;
    const __half* t1 = warped + (size_t)n1 * HW;
    int tid = threadIdx.x;

    for (int i = tid; i < 34 * 10; i += 256) {
        int ly = i / 10, c = i - (i / 10) * 10;
        int gy = oy0 + ly - 1;
        int gx = ox0 - 4 + c * 4;                 // 8B/16B-aligned chunks
        float4 tv0 = {0, 0, 0, 0}, tv1 = {0, 0, 0, 0}, pv = {0, 0, 0, 0};
        if (gy >= 0 && gy < HH && gx >= 0 && gx + 3 < WW) {
            union { uint2 u; __half2 h2[2]; } cv;
            cv.u = *(const uint2*)(t0 + gy * WW + gx);
            float2 lo = __half22float2(cv.h2[0]);
            float2 hi = __half22float2(cv.h2[1]);
            tv0 = make_float4(lo.x, lo.y, hi.x, hi.y);
            cv.u = *(const uint2*)(t1 + gy * WW + gx);
            lo = __half22float2(cv.h2[0]);
            hi = __half22float2(cv.h2[1]);
            tv1 = make_float4(lo.x, lo.y, hi.x, hi.y);
            pv = *(const float4*)(templ + gy * WW + gx);
        }
        *(float4*)&st0[ly][c * 4] = tv0;
        *(float4*)&st1[ly][c * 4] = tv1;
        *(float4*)&sp[ly][c * 4] = pv;
    }
    __syncthreads();

    int tx = tid & 7, ty = tid >> 3;   // ty: output row 0..31, xb: x base
    int xb = tx * 4;
    float cA[6] = {0,0,0,0,0,0}, cA2[6] = {0,0,0,0,0,0}, cAP[6] = {0,0,0,0,0,0};
    float cB[6] = {0,0,0,0,0,0}, cB2[6] = {0,0,0,0,0,0}, cBP[6] = {0,0,0,0,0,0};
    float cP[6] = {0,0,0,0,0,0}, cP2[6] = {0,0,0,0,0,0};
    #pragma unroll
    for (int r = 0; r < 3; ++r) {
        float ta0 = st0[ty + r][xb + 3];
        float4 ta4 = *(const float4*)&st0[ty + r][xb + 4];
        float ta5 = st0[ty + r][xb + 8];
        float tb0 = st1[ty + r][xb + 3];
        float4 tb4 = *(const float4*)&st1[ty + r][xb + 4];
        float tb5 = st1[ty + r][xb + 8];
        float p0 = sp[ty + r][xb + 3];
        float4 p4 = *(const float4*)&sp[ty + r][xb + 4];
        float p5 = sp[ty + r][xb + 8];
        float av[6] = {ta0, ta4.x, ta4.y, ta4.z, ta4.w, ta5};
        float bv[6] = {tb0, tb4.x, tb4.y, tb4.z, tb4.w, tb5};
        float pv[6] = {p0, p4.x, p4.y, p4.z, p4.w, p5};
        #pragma unroll
        for (int c = 0; c < 6; ++c) {
            cA[c] += av[c]; cB[c] += bv[c]; cP[c] += pv[c];
            cA2[c] = fmaf(av[c], av[c], cA2[c]);
            cB2[c] = fmaf(bv[c], bv[c], cB2[c]);
            cP2[c] = fmaf(pv[c], pv[c], cP2[c]);
            cAP[c] = fmaf(av[c], pv[c], cAP[c]);
            cBP[c] = fmaf(bv[c], pv[c], cBP[c]);
        }
    }
    const float inv9 = 1.f / 9.f;
    float ncc0 = 0.f, ncc1 = 0.f;
    #pragma unroll
    for (int j = 0; j < 4; ++j) {
        float ps = cP[j] + cP[j + 1] + cP[j + 2];
        float p2s = cP2[j] + cP2[j + 1] + cP2[j + 2];
        float pvar = fmaxf(p2s - (ps * inv9) * ps, 0.f);
        {
            float ts = cA[j] + cA[j + 1] + cA[j + 2];
            float t2s = cA2[j] + cA2[j + 1] + cA2[j + 2];
            float tps = cAP[j] + cAP[j + 1] + cAP[j + 2];
            float cross = tps - (ps * inv9) * ts;
            float tvar = fmaxf(t2s - (ts * inv9) * ts, 0.f);
            ncc0 += (cross * cross) / (tvar * pvar + 1e-5f);
        }
        {
            float ts = cB[j] + cB[j + 1] + cB[j + 2];
            float t2s = cB2[j] + cB2[j + 1] + cB2[j + 2];
            float tps = cBP[j] + cBP[j + 1] + cBP[j + 2];
            float cross = tps - (ps * inv9) * ts;
            float tvar = fmaxf(t2s - (ts * inv9) * ts, 0.f);
            ncc1 += (cross * cross) / (tvar * pvar + 1e-5f);
        }
    }
    block_reduce_store2_256(ncc0, ncc1,
                            &partialsN[(size_t)n0 * K3_TILES + tile],
                            &partialsN[(size_t)n1 * K3_TILES + tile]);
}

// ---- K4: final reduction (double) ------------------------------------------
__global__ __launch_bounds__(1024) void finalize_kernel(
        const float* __restrict__ pN, const float* __restrict__ pG,
        float* __restrict__ out) {
    double accN = 0.0, accG = 0.0;
    for (int i = threadIdx.x; i < NP_N; i += 1024) accN += (double)pN[i];
    for (int i = threadIdx.x; i < NP_G; i += 1024) accG += (double)pG[i];
    #pragma unroll
    for (int o = 32; o > 0; o >>= 1) {
        accN += __shfl_down(accN, o);
        accG += __shfl_down(accG, o);
    }
    __shared__ double sN[16], sG[16];
    int wave = threadIdx.x >> 6, lane = threadIdx.x & 63;
    if (lane == 0) { sN[wave] = accN; sG[wave] = accG; }
    __syncthreads();
    if (threadIdx.x == 0) {
        double tN = 0.0, tG = 0.0;
        #pragma unroll
        for (int w = 0; w < 16; ++w) { tN += sN[w]; tG += sG[w]; }
        double lncc = -(tN / (double)NPIX);
        double g2 = tG / (2.0 * GRAD_CNT);
        out[0] = (float)(lncc + g2);
    }
}

extern "C" void kernel_launch(void* const* d_in, const int* in_sizes, int n_in,
                              void* d_out, int out_size, void* d_ws, size_t ws_size,
                              hipStream_t stream) {
    const float* images = (const float*)d_in[0];
    const float* warps  = (const float*)d_in[1];
    float* out = (float*)d_out;

    __half* warped  = (__half*)d_ws;                          // NPIX halves
    float* fbase    = (float*)((char*)d_ws + (size_t)NPIX * 2);
    float* partialsN = fbase;                     // NP_N floats
    float* partialsG = partialsN + NP_N;          // NP_G floats
    float* tpart     = partialsG + NP_G;          // 8*HW floats
    float* templ     = tpart + (size_t)K2_SPLIT * HW; // HW floats

    warp_grad_kernel<<<dim3(K1_NT, NIMG), dim3(256), 0, stream>>>(
        images, warps, warped, partialsG);
    template_part_kernel<<<dim3(HW / 8 / 256, K2_SPLIT), dim3(256), 0, stream>>>(
        warped, tpart);
    template_combine_kernel<<<dim3(HW / 4 / 256), dim3(256), 0, stream>>>(
        tpart, templ);
    lncc_kernel<<<dim3(K3_TILES, 64), dim3(256), 0, stream>>>(
        warped, templ, partialsN);
    finalize_kernel<<<dim3(1), dim3(1024), 0, stream>>>(
        partialsN, partialsG, out);
}

// Round 17
// 105.443 us; speedup vs baseline: 1.1444x; 1.1444x over previous
//
#include <hip/hip_runtime.h>
#include <hip/hip_fp16.h>

#define HH 384
#define WW 384
#define HW (HH * WW)            // 147456
#define NIMG 128                // B*G
#define NPIX (NIMG * HW)        // 18874368
#define GRAD_CNT 37650432.0

// K1: full-width tiles, 32 rows, +/-3 staged margin, 38 pair-rows LDS (58.4 KB)
// 1024 threads, 2 blocks/CU -> 32 waves/CU (100% cap). x-pair layout:
// element (r,x) = half2(img[r][x], img[r][min(x+1,383)]).
#define K1_TH 32
#define K1_M  3
#define K1_NT (HH / K1_TH)              // 12
#define K1_SROWS (K1_TH + 2 * K1_M)     // 38
#define K1_BLOCKS (K1_NT * NIMG)        // 1536
#define NP_G K1_BLOCKS                  // 1536

// K2: n-split into 8 partial template planes, combined once by K2b
#define K2_SPLIT 8

// K3 tiling: 32x32 tiles, 2 n-planes per block, staged window 40 cols
#define K3_T 32
#define K3_NX (WW / K3_T)               // 12
#define K3_TILES (K3_NX * (HH / K3_T)) // 144
#define NP_N (K3_TILES * NIMG)          // 18432

// ---- block reductions ------------------------------------------------------
__device__ inline void block_reduce_store_1024(float v, float* dst) {
    #pragma unroll
    for (int o = 32; o > 0; o >>= 1) v += __shfl_down(v, o);
    __shared__ float s[16];
    int wave = threadIdx.x >> 6, lane = threadIdx.x & 63;
    if (lane == 0) s[wave] = v;
    __syncthreads();
    if (threadIdx.x == 0) {
        float t = 0.f;
        #pragma unroll
        for (int w = 0; w < 16; ++w) t += s[w];
        *dst = t;
    }
}

__device__ inline void block_reduce_store2_256(float v0, float v1,
                                               float* d0, float* d1) {
    #pragma unroll
    for (int o = 32; o > 0; o >>= 1) {
        v0 += __shfl_down(v0, o);
        v1 += __shfl_down(v1, o);
    }
    __shared__ float s0[4], s1[4];
    int wave = threadIdx.x >> 6, lane = threadIdx.x & 63;
    if (lane == 0) { s0[wave] = v0; s1[wave] = v1; }
    __syncthreads();
    if (threadIdx.x == 0) {
        *d0 = s0[0] + s0[1] + s0[2] + s0[3];
        *d1 = s1[0] + s1[1] + s1[2] + s1[3];
    }
}

// ---- K1: bilinear warp (x-pair fp16 LDS), 1024 thr, XCD-swizzled grid ------
__global__ __launch_bounds__(1024, 2) void warp_grad_kernel(
        const float* __restrict__ images, const float* __restrict__ warps,
        __half* __restrict__ warped, float* __restrict__ partialsG) {
    __shared__ __half2 simg[K1_SROWS * WW];      // 58.4 KB
    // XCD-bijective swizzle: XCD k owns contiguous tile range [k*192,(k+1)*192)
    int sw = (blockIdx.x & 7) * (K1_BLOCKS / 8) + (blockIdx.x >> 3);
    int n  = sw / K1_NT;
    int yt = sw - n * K1_NT;
    int y0 = yt * K1_TH;
    int ys0 = max(0, y0 - K1_M);
    int ys1 = min(HH - 1, y0 + K1_TH - 1 + K1_M);
    int cnt = ys1 - ys0 + 1;                  // <= 38
    const float* img = images + (size_t)n * HW;
    int tid = threadIdx.x;

    // stage pair-rows [ys0, ys1]: float4 read + shfl neighbor -> 4 half2 pairs
    for (int i = tid; i < cnt * 96; i += 1024) {
        int r = i / 96, gg = i - r * 96;
        int x0 = gg * 4;
        const float* rowp = img + (ys0 + r) * WW + x0;
        float4 v = *(const float4*)rowp;
        float nb = __shfl_down(v.x, 1);       // next group's first element
        if (gg == 95) nb = v.w;               // row edge: duplicate
        else if ((tid & 63) == 63) nb = rowp[4];  // wave edge: scalar load
        union { __half2 h[4]; uint4 u; } pk;
        pk.h[0] = __floats2half2_rn(v.x, v.y);
        pk.h[1] = __floats2half2_rn(v.y, v.z);
        pk.h[2] = __floats2half2_rn(v.z, v.w);
        pk.h[3] = __floats2half2_rn(v.w, nb);
        *(uint4*)(simg + r * WW + x0) = pk.u; // 16B-aligned ds_write_b128
    }
    __syncthreads();

    const float* flow0 = warps + (size_t)n * 2 * HW;
    const float* flow1 = flow0 + HW;
    float g = 0.f;

    #pragma unroll
    for (int gi = 0; gi < 3; ++gi) {          // 32 rows * 96 groups = 3 * 1024
        int p4 = gi * 1024 + tid;
        int r = p4 / 96;                      // tile row 0..31
        int c4 = p4 - r * 96;
        int x0 = c4 * 4;
        int y = y0 + r;
        int base = y * WW + x0;

        float4 f0 = *(const float4*)(flow0 + base);
        float4 f1 = *(const float4*)(flow1 + base);

        // right-neighbor first element via cross-lane (saves 2 scalar VMEM)
        float a0 = __shfl_down(f0.x, 1);
        float a1 = __shfl_down(f1.x, 1);
        if (c4 == 95) {                       // row edge: self-zero diff
            a0 = f0.w; a1 = f1.w;
        } else if ((tid & 63) == 63) {        // wave edge: 1-lane load
            a0 = flow0[base + 4]; a1 = flow1[base + 4];
        }

        // grad2d l2: dx within group + right neighbor, dy vs next row
        float d;
        d = f0.y - f0.x; g += d * d;  d = f1.y - f1.x; g += d * d;
        d = f0.z - f0.y; g += d * d;  d = f1.z - f1.y; g += d * d;
        d = f0.w - f0.z; g += d * d;  d = f1.w - f1.z; g += d * d;
        d = a0 - f0.w;   g += d * d;  d = a1 - f1.w;   g += d * d;
        if (y + 1 < HH) {
            float4 b0 = *(const float4*)(flow0 + base + WW);
            float4 b1 = *(const float4*)(flow1 + base + WW);
            d = b0.x - f0.x; g += d * d;  d = b1.x - f1.x; g += d * d;
            d = b0.y - f0.y; g += d * d;  d = b1.y - f1.y; g += d * d;
            d = b0.z - f0.z; g += d * d;  d = b1.z - f1.z; g += d * d;
            d = b0.w - f0.w; g += d * d;  d = b1.w - f1.w; g += d * d;
        }

        float fxa[4] = {f0.x, f0.y, f0.z, f0.w};
        float fya[4] = {f1.x, f1.y, f1.z, f1.w};

        // clamped coordinates (exact: out-of-range tap weights collapse)
        float cxc[4], cyc[4];
        #pragma unroll
        for (int j = 0; j < 4; ++j) {
            cxc[j] = fminf(fmaxf((float)(x0 + j) + fxa[j], 0.f), 383.f);
            cyc[j] = fminf(fmaxf((float)y + fya[j], 0.f), 383.f);
        }
        bool ok = true;
        #pragma unroll
        for (int j = 0; j < 4; ++j) {
            int yi = (int)cyc[j];
            ok = ok && (yi >= ys0) && (yi < ys1);
        }

        float o[4];
        if (ok) {
            // fast path: 2 ds_read_b32 per pixel, single address
            #pragma unroll
            for (int j = 0; j < 4; ++j) {
                int xi = (int)cxc[j], yi = (int)cyc[j];
                float wx = cxc[j] - (float)xi, wy = cyc[j] - (float)yi;
                const __half2* rp = simg + (yi - ys0) * WW + xi;
                float2 tp = __half22float2(rp[0]);
                float2 bt = __half22float2(rp[WW]);
                float top = fmaf(wx, tp.y - tp.x, tp.x);
                float bot = fmaf(wx, bt.y - bt.x, bt.x);
                o[j] = fmaf(wy, bot - top, top);
            }
        } else {
            // slow path (~1% of groups): exact f32 global taps
            #pragma unroll
            for (int j = 0; j < 4; ++j) {
                int xi = (int)cxc[j], yi = (int)cyc[j];
                float wx = cxc[j] - (float)xi, wy = cyc[j] - (float)yi;
                int x1 = min(xi + 1, WW - 1), y1 = min(yi + 1, HH - 1);
                float v00 = img[yi * WW + xi], v01 = img[yi * WW + x1];
                float v10 = img[y1 * WW + xi], v11 = img[y1 * WW + x1];
                float top = fmaf(wx, v01 - v00, v00);
                float bot = fmaf(wx, v11 - v10, v10);
                o[j] = fmaf(wy, bot - top, top);
            }
        }
        union { __half2 h2[2]; uint2 u; } cv;
        cv.h2[0] = __floats2half2_rn(o[0], o[1]);
        cv.h2[1] = __floats2half2_rn(o[2], o[3]);
        *(uint2*)(warped + (size_t)n * HW + base) = cv.u;
    }
    block_reduce_store_1024(g, &partialsG[sw]);
}

// ---- K2a: partial template sums (n split 8-ways, 8 px/thread, fp16 in) -----
__global__ __launch_bounds__(256) void template_part_kernel(
        const __half* __restrict__ warped, float* __restrict__ tpart) {
    int p8 = blockIdx.x * 256 + threadIdx.x;      // < HW/8 (grid.x = 72)
    int q = blockIdx.y;                           // 0..7
    const __half* p = warped + (size_t)q * (NIMG / K2_SPLIT) * HW + p8 * 8;
    float s[8] = {0, 0, 0, 0, 0, 0, 0, 0};
    #pragma unroll 4
    for (int nn = 0; nn < NIMG / K2_SPLIT; ++nn) {
        union { uint4 u; __half2 h2[4]; } cv;
        cv.u = *(const uint4*)(p + (size_t)nn * HW);
        #pragma unroll
        for (int k = 0; k < 4; ++k) {
            float2 f = __half22float2(cv.h2[k]);
            s[2 * k] += f.x; s[2 * k + 1] += f.y;
        }
    }
    float* dst = tpart + (size_t)q * HW + p8 * 8;
    *(float4*)dst       = make_float4(s[0], s[1], s[2], s[3]);
    *(float4*)(dst + 4) = make_float4(s[4], s[5], s[6], s[7]);
}

// ---- K2b: combine 8 planes -> templ (f32) ----------------------------------
__global__ __launch_bounds__(256) void template_combine_kernel(
        const float* __restrict__ tpart, float* __restrict__ templ) {
    int p4 = blockIdx.x * 256 + threadIdx.x;      // < HW/4 (144 blocks)
    float sx = 0, sy = 0, sz = 0, sw = 0;
    #pragma unroll
    for (int pl = 0; pl < K2_SPLIT; ++pl) {
        float4 a = *(const float4*)(tpart + (size_t)pl * HW + p4 * 4);
        sx += a.x; sy += a.y; sz += a.z; sw += a.w;
    }
    const float sc = 1.f / (float)NIMG;
    *(float4*)(templ + p4 * 4) = make_float4(sx * sc, sy * sc, sz * sc, sw * sc);
}

// ---- K3: LNCC, 2 n-planes per block, shared template stage -----------------
__global__ __launch_bounds__(256) void lncc_kernel(
        const __half* __restrict__ warped, const float* __restrict__ templ,
        float* __restrict__ partialsN) {
    __shared__ float st0[34][40];
    __shared__ float st1[34][40];
    __shared__ float sp[34][40];
    int n0 = blockIdx.y;                   // 0..63
    int n1 = n0 + 64;
    int tile = blockIdx.x;
    int tyt = tile / K3_NX, txt = tile - tyt * K3_NX;
    int oy0 = tyt * K3_T, ox0 = txt * K3_T;
    const __half* t0 = warped + (size_t)n0 * HW;
    const __half* t1 = warped + (size_t)n1 * HW;
    int tid = threadIdx.x;

    for (int i = tid; i < 34 * 10; i += 256) {
        int ly = i / 10, c = i - (i / 10) * 10;
        int gy = oy0 + ly - 1;
        int gx = ox0 - 4 + c * 4;                 // 8B/16B-aligned chunks
        float4 tv0 = {0, 0, 0, 0}, tv1 = {0, 0, 0, 0}, pv = {0, 0, 0, 0};
        if (gy >= 0 && gy < HH && gx >= 0 && gx + 3 < WW) {
            union { uint2 u; __half2 h2[2]; } cv;
            cv.u = *(const uint2*)(t0 + gy * WW + gx);
            float2 lo = __half22float2(cv.h2[0]);
            float2 hi = __half22float2(cv.h2[1]);
            tv0 = make_float4(lo.x, lo.y, hi.x, hi.y);
            cv.u = *(const uint2*)(t1 + gy * WW + gx);
            lo = __half22float2(cv.h2[0]);
            hi = __half22float2(cv.h2[1]);
            tv1 = make_float4(lo.x, lo.y, hi.x, hi.y);
            pv = *(const float4*)(templ + gy * WW + gx);
        }
        *(float4*)&st0[ly][c * 4] = tv0;
        *(float4*)&st1[ly][c * 4] = tv1;
        *(float4*)&sp[ly][c * 4] = pv;
    }
    __syncthreads();

    int tx = tid & 7, ty = tid >> 3;   // ty: output row 0..31, xb: x base
    int xb = tx * 4;
    float cA[6] = {0,0,0,0,0,0}, cA2[6] = {0,0,0,0,0,0}, cAP[6] = {0,0,0,0,0,0};
    float cB[6] = {0,0,0,0,0,0}, cB2[6] = {0,0,0,0,0,0}, cBP[6] = {0,0,0,0,0,0};
    float cP[6] = {0,0,0,0,0,0}, cP2[6] = {0,0,0,0,0,0};
    #pragma unroll
    for (int r = 0; r < 3; ++r) {
        float ta0 = st0[ty + r][xb + 3];
        float4 ta4 = *(const float4*)&st0[ty + r][xb + 4];
        float ta5 = st0[ty + r][xb + 8];
        float tb0 = st1[ty + r][xb + 3];
        float4 tb4 = *(const float4*)&st1[ty + r][xb + 4];
        float tb5 = st1[ty + r][xb + 8];
        float p0 = sp[ty + r][xb + 3];
        float4 p4 = *(const float4*)&sp[ty + r][xb + 4];
        float p5 = sp[ty + r][xb + 8];
        float av[6] = {ta0, ta4.x, ta4.y, ta4.z, ta4.w, ta5};
        float bv[6] = {tb0, tb4.x, tb4.y, tb4.z, tb4.w, tb5};
        float pv[6] = {p0, p4.x, p4.y, p4.z, p4.w, p5};
        #pragma unroll
        for (int c = 0; c < 6; ++c) {
            cA[c] += av[c]; cB[c] += bv[c]; cP[c] += pv[c];
            cA2[c] = fmaf(av[c], av[c], cA2[c]);
            cB2[c] = fmaf(bv[c], bv[c], cB2[c]);
            cP2[c] = fmaf(pv[c], pv[c], cP2[c]);
            cAP[c] = fmaf(av[c], pv[c], cAP[c]);
            cBP[c] = fmaf(bv[c], pv[c], cBP[c]);
        }
    }
    const float inv9 = 1.f / 9.f;
    float ncc0 = 0.f, ncc1 = 0.f;
    #pragma unroll
    for (int j = 0; j < 4; ++j) {
        float ps = cP[j] + cP[j + 1] + cP[j + 2];
        float p2s = cP2[j] + cP2[j + 1] + cP2[j + 2];
        float pvar = fmaxf(p2s - (ps * inv9) * ps, 0.f);
        {
            float ts = cA[j] + cA[j + 1] + cA[j + 2];
            float t2s = cA2[j] + cA2[j + 1] + cA2[j + 2];
            float tps = cAP[j] + cAP[j + 1] + cAP[j + 2];
            float cross = tps - (ps * inv9) * ts;
            float tvar = fmaxf(t2s - (ts * inv9) * ts, 0.f);
            ncc0 += (cross * cross) / (tvar * pvar + 1e-5f);
        }
        {
            float ts = cB[j] + cB[j + 1] + cB[j + 2];
            float t2s = cB2[j] + cB2[j + 1] + cB2[j + 2];
            float tps = cBP[j] + cBP[j + 1] + cBP[j + 2];
            float cross = tps - (ps * inv9) * ts;
            float tvar = fmaxf(t2s - (ts * inv9) * ts, 0.f);
            ncc1 += (cross * cross) / (tvar * pvar + 1e-5f);
        }
    }
    block_reduce_store2_256(ncc0, ncc1,
                            &partialsN[(size_t)n0 * K3_TILES + tile],
                            &partialsN[(size_t)n1 * K3_TILES + tile]);
}

// ---- K4: final reduction (double) ------------------------------------------
__global__ __launch_bounds__(1024) void finalize_kernel(
        const float* __restrict__ pN, const float* __restrict__ pG,
        float* __restrict__ out) {
    double accN = 0.0, accG = 0.0;
    for (int i = threadIdx.x; i < NP_N; i += 1024) accN += (double)pN[i];
    for (int i = threadIdx.x; i < NP_G; i += 1024) accG += (double)pG[i];
    #pragma unroll
    for (int o = 32; o > 0; o >>= 1) {
        accN += __shfl_down(accN, o);
        accG += __shfl_down(accG, o);
    }
    __shared__ double sN[16], sG[16];
    int wave = threadIdx.x >> 6, lane = threadIdx.x & 63;
    if (lane == 0) { sN[wave] = accN; sG[wave] = accG; }
    __syncthreads();
    if (threadIdx.x == 0) {
        double tN = 0.0, tG = 0.0;
        #pragma unroll
        for (int w = 0; w < 16; ++w) { tN += sN[w]; tG += sG[w]; }
        double lncc = -(tN / (double)NPIX);
        double g2 = tG / (2.0 * GRAD_CNT);
        out[0] = (float)(lncc + g2);
    }
}

extern "C" void kernel_launch(void* const* d_in, const int* in_sizes, int n_in,
                              void* d_out, int out_size, void* d_ws, size_t ws_size,
                              hipStream_t stream) {
    const float* images = (const float*)d_in[0];
    const float* warps  = (const float*)d_in[1];
    float* out = (float*)d_out;

    __half* warped  = (__half*)d_ws;                          // NPIX halves
    float* fbase    = (float*)((char*)d_ws + (size_t)NPIX * 2);
    float* partialsN = fbase;                     // NP_N floats
    float* partialsG = partialsN + NP_N;          // NP_G floats
    float* tpart     = partialsG + NP_G;          // 8*HW floats
    float* templ     = tpart + (size_t)K2_SPLIT * HW; // HW floats

    warp_grad_kernel<<<dim3(K1_BLOCKS), dim3(1024), 0, stream>>>(
        images, warps, warped, partialsG);
    template_part_kernel<<<dim3(HW / 8 / 256, K2_SPLIT), dim3(256), 0, stream>>>(
        warped, tpart);
    template_combine_kernel<<<dim3(HW / 4 / 256), dim3(256), 0, stream>>>(
        tpart, templ);
    lncc_kernel<<<dim3(K3_TILES, 64), dim3(256), 0, stream>>>(
        warped, templ, partialsN);
    finalize_kernel<<<dim3(1), dim3(1024), 0, stream>>>(
        partialsN, partialsG, out);
}